// Round 3
// 919.063 us; speedup vs baseline: 1.2167x; 1.2167x over previous
//
#include <hip/hip_runtime.h>

// ---------------- problem constants ----------------
#define NBATCH 32
#define LSEQ   2048
#define CDIM   256
#define KDIM   1024
#define DEMI   8
#define H1DIM  40
#define DEMO   20
#define NCHUNK 32
#define CHLEN  64
#define LNEPS  1e-5f

// ---- ws layout (float element offsets) ----
#define OFF_X    0L            // 32*2048*256 = 16777216  (X, overwritten in-place by p_max)
#define OFF_S    16777216L     // cumsum, 16777216
#define OFF_AGM  33554432L     // 32*32*256 = 262144 (agm+ags aliased as Wf bf16[786432] pre-GEMM)
#define OFF_AGS  33816576L
#define OFF_AGI  34078720L     // int
#define OFF_PRM  34340864L
#define OFF_PRS  34603008L
#define OFF_PRI  34865152L     // int
#define OFF_DV   35127296L     // 32*20
#define OFF_BASE 35127936L     // 32*256
// total 35136128 floats = 140.5 MB

// ---- d_out sections (float element offsets) ----
#define OUT0_OFF   0L          // [32,2048,788]
#define OUTTI_OFF  51642368L   // [32,256,2048]
#define OUTACT_OFF 68419584L   // [32,256,2048]

typedef short          s16x8 __attribute__((ext_vector_type(8)));   // 8 bf16 (4 VGPR) MFMA frag
typedef unsigned short us4   __attribute__((ext_vector_type(4)));
typedef float          f32x4 __attribute__((ext_vector_type(4)));

// branch-free RNE float->bf16 on raw bits (inputs finite)
static __device__ __forceinline__ unsigned short f2bf(float x) {
    unsigned u = __builtin_bit_cast(unsigned, x);
    u += 0x7fffu + ((u >> 16) & 1u);
    return (unsigned short)(u >> 16);
}
static __device__ __forceinline__ float bf2f(unsigned short h) {
    return __builtin_bit_cast(float, ((unsigned)h) << 16);
}

// ---------------------------------------------------------------------------
// K1: dem MLP (8->40->20, ReLU) + fold dem & b_lin into per-(n,c) base
// ---------------------------------------------------------------------------
__global__ __launch_bounds__(256) void k_dem(
    const float* __restrict__ dem,
    const float* __restrict__ W1, const float* __restrict__ b1,
    const float* __restrict__ W2, const float* __restrict__ b2,
    const float* __restrict__ Wl, const float* __restrict__ bl,
    float* __restrict__ dvals, float* __restrict__ base)
{
    __shared__ float h1[NBATCH][H1DIM];
    __shared__ float dsh[NBATCH][DEMO];
    int tid = threadIdx.x;

    for (int idx = tid; idx < NBATCH * H1DIM; idx += 256) {
        int n = idx / H1DIM, o = idx % H1DIM;
        float s = b1[o];
        #pragma unroll
        for (int k = 0; k < DEMI; ++k) s += dem[n * DEMI + k] * W1[k * H1DIM + o];
        h1[n][o] = fmaxf(s, 0.0f);
    }
    __syncthreads();
    for (int idx = tid; idx < NBATCH * DEMO; idx += 256) {
        int n = idx / DEMO, o = idx % DEMO;
        float s = b2[o];
        #pragma unroll
        for (int k = 0; k < H1DIM; ++k) s += h1[n][k] * W2[k * DEMO + o];
        float dv = fmaxf(s, 0.0f);
        dsh[n][o] = dv;
        dvals[idx] = dv;
    }
    __syncthreads();
    for (int idx = tid; idx < NBATCH * CDIM; idx += 256) {
        int n = idx >> 8, c = idx & 255;
        float s = bl[c];
        #pragma unroll
        for (int k = 0; k < DEMO; ++k) s += dsh[n][k] * Wl[(KDIM + k) * CDIM + c];
        base[idx] = s;
    }
}

// ---------------------------------------------------------------------------
// K1b: pre-convert W (1024x256 fp32) into 3-way bf16 split, MFMA-frag layout.
// w = h + m + l (bf16 each, RNE; Sterbenz-exact residuals, never subnormal).
// Wf layout (bf16/u16 units): [kstep:32][plane:3][ntile:16][lane:64][e:8]
//   lane = (c&15) + 16*((k&31)>>3), e = k&7.  Total 1.5 MB (aliases agm+ags).
// ---------------------------------------------------------------------------
__global__ __launch_bounds__(256) void k_wconv(
    const float* __restrict__ W, unsigned short* __restrict__ Wf)
{
    int idx = blockIdx.x * 256 + threadIdx.x;   // 0..262143
    int k = idx >> 8, c = idx & 255;
    float w = W[idx];
    unsigned short h = f2bf(w);
    float r1 = w - bf2f(h);
    unsigned short m = f2bf(r1);
    float r2 = r1 - bf2f(m);
    unsigned short l = f2bf(r2);
    int kstep = k >> 5;
    int nt = c >> 4;
    int ln = (c & 15) + (((k & 31) >> 3) << 4);
    int e = k & 7;
    long o = (((long)(kstep * 3) * 16 + nt) * 64 + ln) * 8 + e;
    Wf[o]         = h;    // plane stride = 16*64*8 = 8192 u16
    Wf[o + 8192]  = m;
    Wf[o + 16384] = l;
}

// ---------------------------------------------------------------------------
// K2: 3-way-bf16-split MFMA GEMM.  X = ts @ W + base.
// a = ah+am+al, b = bh+bm+bl; a*b ~= ah*bh + ah*bm + am*bh + ah*bl + al*bh + am*bm
// (dropped terms <= 2^-24 worst, ~2^-29 rms: X error ~4e-7 < fp32-chain error).
// Tile BM=128 x BN=128, BK=32, 256 thr = 4 waves (2x2), 64x64/wave,
// acc[4][4] 16x16 tiles via v_mfma_f32_16x16x32_bf16 (K=32 per MFMA).
// ---------------------------------------------------------------------------
__global__ __launch_bounds__(256) void k_gemm(
    const float* __restrict__ ts0, const float* __restrict__ ts1,
    const float* __restrict__ ts2, const float* __restrict__ ts3,
    const unsigned short* __restrict__ Wf, const float* __restrict__ base,
    float* __restrict__ X)
{
    __shared__ unsigned short Af[3][8][64][8];   // [plane][mtile][lane][e] 24 KB
    __shared__ unsigned short Bf[3][8][64][8];   // [plane][ntile][lane][e] 24 KB

    const int tid  = threadIdx.x;
    const int lane = tid & 63;
    const int wid  = tid >> 6;

    const int mb = blockIdx.x >> 1;        // 0..511
    const int cb = (blockIdx.x & 1) << 7;  // 0 / 128
    const int n  = mb >> 4;
    const int t0 = (mb & 15) << 7;

    // A staging: thread -> (row am, k-comb kq); per j loads float4 at k=4*kq+8*j.
    const int kq  = tid & 1;
    const int am  = tid >> 1;              // 0..127
    const int amt = am >> 4, aml = am & 15;
    const long arow = ((long)(n * LSEQ + t0 + am)) * CDIM;

    f32x4 acc[4][4];
    #pragma unroll
    for (int i = 0; i < 4; ++i)
        #pragma unroll
        for (int j = 0; j < 4; ++j)
            #pragma unroll
            for (int r = 0; r < 4; ++r) acc[i][j][r] = 0.0f;

    const uint4* wsrc = (const uint4*)Wf;            // 16B units
    uint4* bdst = (uint4*)(&Bf[0][0][0][0]);

    for (int k0 = 0; k0 < KDIM; k0 += 32) {
        const float* tsp = (k0 < 256) ? ts0 : (k0 < 512) ? ts1 : (k0 < 768) ? ts2 : ts3;
        const int joff = k0 & 255;

        // prefetch A (fp32) and B (bf16-frag chunks) into regs
        float4 av[4];
        #pragma unroll
        for (int j = 0; j < 4; ++j)
            av[j] = *(const float4*)(tsp + arow + joff + kq * 4 + j * 8);

        const int kstep = k0 >> 5;
        // uint4 units: plane = 1024, kstep = 3072; block slice starts at (cb>>4)*64
        const long wbase = (long)kstep * 3072 + ((cb >> 4) << 6);
        uint4 bv[6];
        #pragma unroll
        for (int p = 0; p < 3; ++p) {
            bv[p * 2 + 0] = wsrc[wbase + p * 1024 + tid];
            bv[p * 2 + 1] = wsrc[wbase + p * 1024 + tid + 256];
        }

        __syncthreads();   // previous tile fully consumed

        // convert fp32 -> (h,m,l) bf16 and write A fragments (3 planes)
        #pragma unroll
        for (int j = 0; j < 4; ++j) {
            const float vv[4] = {av[j].x, av[j].y, av[j].z, av[j].w};
            us4 hv, mv, lv;
            #pragma unroll
            for (int q = 0; q < 4; ++q) {
                float v = vv[q];
                unsigned short h = f2bf(v);
                float r1 = v - bf2f(h);
                unsigned short m = f2bf(r1);
                float r2 = r1 - bf2f(m);
                unsigned short l = f2bf(r2);
                hv[q] = h; mv[q] = m; lv[q] = l;
            }
            const int ln = aml + (j << 4);     // k>>3 == j
            const int e0 = kq << 2;            // k&7 == 4*kq
            *(us4*)&Af[0][amt][ln][e0] = hv;
            *(us4*)&Af[1][amt][ln][e0] = mv;
            *(us4*)&Af[2][amt][ln][e0] = lv;
        }
        // B: linear copy (layout already fragment-order)
        #pragma unroll
        for (int p = 0; p < 3; ++p) {
            bdst[p * 512 + tid]       = bv[p * 2 + 0];
            bdst[p * 512 + tid + 256] = bv[p * 2 + 1];
        }

        __syncthreads();

        // compute: wave quadrant (wmt, wnt), 16 tiles x 6 MFMAs
        const int wmt = (wid >> 1) << 2;
        const int wnt = (wid & 1) << 2;
        s16x8 ah[4], am2[4], al2[4];
        #pragma unroll
        for (int mt = 0; mt < 4; ++mt) {
            ah[mt]  = *(const s16x8*)&Af[0][wmt + mt][lane][0];
            am2[mt] = *(const s16x8*)&Af[1][wmt + mt][lane][0];
            al2[mt] = *(const s16x8*)&Af[2][wmt + mt][lane][0];
        }
        #pragma unroll
        for (int nt = 0; nt < 4; ++nt) {
            s16x8 bh = *(const s16x8*)&Bf[0][wnt + nt][lane][0];
            s16x8 bm = *(const s16x8*)&Bf[1][wnt + nt][lane][0];
            s16x8 bl = *(const s16x8*)&Bf[2][wnt + nt][lane][0];
            #pragma unroll
            for (int mt = 0; mt < 4; ++mt) {
                acc[mt][nt] = __builtin_amdgcn_mfma_f32_16x16x32_bf16(ah[mt],  bl, acc[mt][nt], 0, 0, 0);
                acc[mt][nt] = __builtin_amdgcn_mfma_f32_16x16x32_bf16(al2[mt], bh, acc[mt][nt], 0, 0, 0);
                acc[mt][nt] = __builtin_amdgcn_mfma_f32_16x16x32_bf16(am2[mt], bm, acc[mt][nt], 0, 0, 0);
                acc[mt][nt] = __builtin_amdgcn_mfma_f32_16x16x32_bf16(ah[mt],  bm, acc[mt][nt], 0, 0, 0);
                acc[mt][nt] = __builtin_amdgcn_mfma_f32_16x16x32_bf16(am2[mt], bh, acc[mt][nt], 0, 0, 0);
                acc[mt][nt] = __builtin_amdgcn_mfma_f32_16x16x32_bf16(ah[mt],  bh, acc[mt][nt], 0, 0, 0);
            }
        }
    }

    // epilogue: C/D layout col=lane&15, row=4*(lane>>4)+r. Lanes 0-15 write
    // 64B-contiguous channel runs -> clean full-line stores.
    const int rb = ((wid >> 1) << 6) + ((lane >> 4) << 2);
    const int cc = cb + ((wid & 1) << 6) + (lane & 15);
    float bb[4];
    #pragma unroll
    for (int nt = 0; nt < 4; ++nt) bb[nt] = base[n * CDIM + cc + nt * 16];

    #pragma unroll
    for (int mt = 0; mt < 4; ++mt) {
        #pragma unroll
        for (int r = 0; r < 4; ++r) {
            long off = ((long)(n * LSEQ) + t0 + rb + mt * 16 + r) * CDIM + cc;
            #pragma unroll
            for (int nt = 0; nt < 4; ++nt)
                X[off + nt * 16] = acc[mt][nt][r] + bb[nt];
        }
    }
}

// ---------------------------------------------------------------------------
// K3a: per-chunk aggregates (max + first-argmax + sum) over 64 t's
// ---------------------------------------------------------------------------
__global__ __launch_bounds__(256) void k_agg(
    const float* __restrict__ X,
    float* __restrict__ agm, float* __restrict__ ags, int* __restrict__ agi)
{
    int c = threadIdx.x;
    int n = blockIdx.x >> 5, ch = blockIdx.x & 31;
    int t0 = ch * CHLEN;
    const float* p = X + ((long)n * LSEQ + t0) * CDIM + c;
    float vm = -3.4e38f; int im = t0; float sm = 0.0f;
    #pragma unroll 4
    for (int tt = 0; tt < CHLEN; ++tt) {
        float v = p[(long)tt * CDIM];
        if (v > vm) { vm = v; im = t0 + tt; }
        sm += v;
    }
    int o = (n * NCHUNK + ch) * CDIM + c;
    agm[o] = vm; ags[o] = sm; agi[o] = im;
}

// ---------------------------------------------------------------------------
// K3b: exclusive prefix over chunks per (n,c)
// ---------------------------------------------------------------------------
__global__ __launch_bounds__(256) void k_pre(
    const float* __restrict__ agm, const float* __restrict__ ags, const int* __restrict__ agi,
    float* __restrict__ prm, float* __restrict__ prs, int* __restrict__ pri)
{
    int c = threadIdx.x;
    int n = blockIdx.x;
    float vm = -3.4e38f; int im = 0; float sm = 0.0f;
    for (int ch = 0; ch < NCHUNK; ++ch) {
        int o = (n * NCHUNK + ch) * CDIM + c;
        prm[o] = vm; pri[o] = im; prs[o] = sm;
        float av = agm[o]; float as = ags[o]; int ai = agi[o];
        if (av > vm) { vm = av; im = ai; }   // earlier chunk wins ties (av must be strictly >)
        sm += as;
    }
}

// ---------------------------------------------------------------------------
// K3c: final scan. Writes p_max_raw (in-place over X), cumsum S, and
//      time_inds (as float) into Ttmp ([n,t,c] order, staged in d_out act section)
// ---------------------------------------------------------------------------
__global__ __launch_bounds__(256) void k_scan(
    float* __restrict__ X, float* __restrict__ S,
    const float* __restrict__ prm, const float* __restrict__ prs, const int* __restrict__ pri,
    float* __restrict__ Ttmp)
{
    int c = threadIdx.x;
    int n = blockIdx.x >> 5, ch = blockIdx.x & 31;
    int t0 = ch * CHLEN;
    int o = (n * NCHUNK + ch) * CDIM + c;
    float vm = prm[o]; int im = pri[o]; float sm = prs[o];
    long rb = ((long)n * LSEQ + t0) * CDIM + c;
    #pragma unroll 4
    for (int tt = 0; tt < CHLEN; ++tt) {
        int t = t0 + tt;
        long idx = rb + (long)tt * CDIM;
        float v = X[idx];
        if (v > vm) { vm = v; im = t; }
        sm += v;
        bool pad = t < (LSEQ - 1);
        float pm = pad ? fmaxf(vm, 0.0f) : vm;
        int ti = (pad && vm <= 0.0f) ? (t - (LSEQ - 1)) : im;
        X[idx] = pm;
        S[idx] = sm;
        Ttmp[idx] = (float)ti;
    }
}

// ---------------------------------------------------------------------------
// K5: tiled transpose per n: [n, t, c] (2048x256) -> [n, c, t] (256x2048)
// ---------------------------------------------------------------------------
__global__ __launch_bounds__(256) void k_tr(
    const float* __restrict__ src, float* __restrict__ dst)
{
    __shared__ float tile[64][65];
    int n  = blockIdx.z;
    int tB = blockIdx.x;   // 0..31
    int cB = blockIdx.y;   // 0..3
    int tid = threadIdx.x;
    int i0 = tid >> 4;     // 0..15
    int j4 = tid & 15;     // 0..15

    const float* sp = src + ((long)n * LSEQ + tB * 64) * CDIM + cB * 64;
    #pragma unroll
    for (int r = 0; r < 4; ++r) {
        int i = i0 + r * 16;
        float4 v = *(const float4*)(sp + (long)i * CDIM + j4 * 4);
        tile[i][j4 * 4 + 0] = v.x;
        tile[i][j4 * 4 + 1] = v.y;
        tile[i][j4 * 4 + 2] = v.z;
        tile[i][j4 * 4 + 3] = v.w;
    }
    __syncthreads();
    float* dp = dst + ((long)n * CDIM + cB * 64) * LSEQ + tB * 64;
    #pragma unroll
    for (int r = 0; r < 4; ++r) {
        int j = i0 + r * 16;   // c within tile
        float4 v;
        v.x = tile[j4 * 4 + 0][j];
        v.y = tile[j4 * 4 + 1][j];
        v.z = tile[j4 * 4 + 2][j];
        v.w = tile[j4 * 4 + 3][j];
        *(float4*)(dp + (long)j * LSEQ + j4 * 4) = v;
    }
}

// ---------------------------------------------------------------------------
// K4: LayerNorm over c for p_max / p_avg / p_sum + dem tail -> out0 [n,t,788]
// ---------------------------------------------------------------------------
__global__ __launch_bounds__(256) void k_ln(
    const float* __restrict__ P, const float* __restrict__ S,
    const float* __restrict__ dvals, float* __restrict__ out0)
{
    int tid = threadIdx.x;
    int wid = tid >> 6, lane = tid & 63;
    long row = (long)blockIdx.x * 4 + wid;  // 0..65535
    int n = (int)(row >> 11);
    int t = (int)(row & 2047);
    long ib = row * CDIM + lane * 4;

    float4 p = *(const float4*)(P + ib);
    float4 s = *(const float4*)(S + ib);

    float sum_p = p.x + p.y + p.z + p.w;
    float sq_p  = p.x * p.x + p.y * p.y + p.z * p.z + p.w * p.w;
    float sum_s = s.x + s.y + s.z + s.w;
    float sq_s  = s.x * s.x + s.y * s.y + s.z * s.z + s.w * s.w;

    #pragma unroll
    for (int off = 32; off > 0; off >>= 1) {
        sum_p += __shfl_xor(sum_p, off);
        sq_p  += __shfl_xor(sq_p, off);
        sum_s += __shfl_xor(sum_s, off);
        sq_s  += __shfl_xor(sq_s, off);
    }

    const float inv = 1.0f / 256.0f;
    float mu_p = sum_p * inv;
    float var_p = sq_p * inv - mu_p * mu_p;
    float mu_s = sum_s * inv;
    float var_s = sq_s * inv - mu_s * mu_s;

    float r1 = 1.0f / sqrtf(var_p + LNEPS);
    const float a = 1.0f / 2048.0f;
    float r2 = a / sqrtf(a * a * var_s + LNEPS);
    float b = 1.0f / sqrtf((float)(t + 1));
    float r3 = b / sqrtf(b * b * var_s + LNEPS);

    float* ob = out0 + row * 788;
    float4 o1 = {(p.x - mu_p) * r1, (p.y - mu_p) * r1, (p.z - mu_p) * r1, (p.w - mu_p) * r1};
    *(float4*)(ob + lane * 4) = o1;
    float4 o2 = {(s.x - mu_s) * r2, (s.y - mu_s) * r2, (s.z - mu_s) * r2, (s.w - mu_s) * r2};
    *(float4*)(ob + 256 + lane * 4) = o2;
    float4 o3 = {(s.x - mu_s) * r3, (s.y - mu_s) * r3, (s.z - mu_s) * r3, (s.w - mu_s) * r3};
    *(float4*)(ob + 512 + lane * 4) = o3;
    if (lane < 5) {
        float4 dv = *(const float4*)(dvals + n * DEMO + lane * 4);
        *(float4*)(ob + 768 + lane * 4) = dv;
    }
}

// ---------------------------------------------------------------------------
extern "C" void kernel_launch(void* const* d_in, const int* in_sizes, int n_in,
                              void* d_out, int out_size, void* d_ws, size_t ws_size,
                              hipStream_t stream)
{
    const float* dem = (const float*)d_in[0];
    const float* ts0 = (const float*)d_in[1];
    const float* ts1 = (const float*)d_in[2];
    const float* ts2 = (const float*)d_in[3];
    const float* ts3 = (const float*)d_in[4];
    const float* W1  = (const float*)d_in[5];
    const float* b1  = (const float*)d_in[6];
    const float* W2  = (const float*)d_in[7];
    const float* b2  = (const float*)d_in[8];
    const float* Wl  = (const float*)d_in[9];
    const float* bl  = (const float*)d_in[10];

    float* ws = (float*)d_ws;
    float* X    = ws + OFF_X;
    float* S    = ws + OFF_S;
    float* agm  = ws + OFF_AGM;
    float* ags  = ws + OFF_AGS;
    int*   agi  = (int*)(ws + OFF_AGI);
    float* prm  = ws + OFF_PRM;
    float* prs  = ws + OFF_PRS;
    int*   pri  = (int*)(ws + OFF_PRI);
    float* dv   = ws + OFF_DV;
    float* base = ws + OFF_BASE;
    // Wf: 786432 u16 = 1.5 MB, aliases agm+ags (dead until k_agg)
    unsigned short* Wf = (unsigned short*)(ws + OFF_AGM);

    float* out    = (float*)d_out;
    float* outTI  = out + OUTTI_OFF;
    float* outACT = out + OUTACT_OFF;

    k_dem<<<1, 256, 0, stream>>>(dem, W1, b1, W2, b2, Wl, bl, dv, base);
    k_wconv<<<1024, 256, 0, stream>>>(Wl, Wf);
    k_gemm<<<1024, 256, 0, stream>>>(ts0, ts1, ts2, ts3, Wf, base, X);
    k_agg<<<NBATCH * NCHUNK, 256, 0, stream>>>(X, agm, ags, agi);
    k_pre<<<NBATCH, 256, 0, stream>>>(agm, ags, agi, prm, prs, pri);
    // Ttmp staged in the activations section of d_out ([n,t,c] order)
    k_scan<<<NBATCH * NCHUNK, 256, 0, stream>>>(X, S, prm, prs, pri, outACT);
    // transpose time_inds: Ttmp [n,t,c] -> outTI [n,c,t]
    k_tr<<<dim3(32, 4, 32), 256, 0, stream>>>(outACT, outTI);
    // transpose activations: P (=X after scan) [n,t,c] -> outACT [n,c,t]
    k_tr<<<dim3(32, 4, 32), 256, 0, stream>>>(X, outACT);
    // LN + concat + dem tail -> out0
    k_ln<<<16384, 256, 0, stream>>>(X, S, dv, out);
}

// Round 4
// 753.509 us; speedup vs baseline: 1.4840x; 1.2197x over previous
//
#include <hip/hip_runtime.h>

// ---------------- problem constants ----------------
#define NBATCH 32
#define LSEQ   2048
#define CDIM   256
#define KDIM   1024
#define DEMI   8
#define H1DIM  40
#define DEMO   20
#define NCHUNK 32
#define CHLEN  64
#define LNEPS  1e-5f

// ---- ws layout (float element offsets) ----
#define OFF_X    0L            // 32*2048*256 = 16777216  (X, overwritten in-place by p_max)
#define OFF_S    16777216L     // cumsum, 16777216
#define OFF_AGM  33554432L     // 32*32*256 = 262144 (agm+ags aliased as Wf bf16[786432] pre-GEMM)
#define OFF_AGS  33816576L
#define OFF_AGI  34078720L     // int
#define OFF_PRM  34340864L
#define OFF_PRS  34603008L
#define OFF_PRI  34865152L     // int
#define OFF_DV   35127296L     // 32*20
#define OFF_BASE 35127936L     // 32*256
// total 35136128 floats = 140.5 MB

// ---- d_out sections (float element offsets) ----
#define OUT0_OFF   0L          // [32,2048,788] (also stages Ttmp pre-k_ln)
#define OUTTI_OFF  51642368L   // [32,256,2048]
#define OUTACT_OFF 68419584L   // [32,256,2048]

typedef short          s16x8 __attribute__((ext_vector_type(8)));   // 8 bf16 (4 VGPR) MFMA frag
typedef unsigned short us4   __attribute__((ext_vector_type(4)));
typedef float          f32x4 __attribute__((ext_vector_type(4)));

// branch-free RNE float->bf16 on raw bits (inputs finite)
static __device__ __forceinline__ unsigned short f2bf(float x) {
    unsigned u = __builtin_bit_cast(unsigned, x);
    u += 0x7fffu + ((u >> 16) & 1u);
    return (unsigned short)(u >> 16);
}
static __device__ __forceinline__ float bf2f(unsigned short h) {
    return __builtin_bit_cast(float, ((unsigned)h) << 16);
}

// ---------------------------------------------------------------------------
// K1: fused  (blocks 0..1023) W pre-convert to 3-way bf16 frag layout
//            (block 1024)     dem MLP + fold dem & b_lin into base
// Wf layout (u16 units): [kstep:32][plane:3][ntile:16][lane:64][e:8]
//   lane = (c&15) + 16*((k&31)>>3), e = k&7.  1.5 MB, aliases agm+ags.
// ---------------------------------------------------------------------------
__global__ __launch_bounds__(256) void k_demwc(
    const float* __restrict__ dem,
    const float* __restrict__ W1, const float* __restrict__ b1,
    const float* __restrict__ W2, const float* __restrict__ b2,
    const float* __restrict__ Wl, const float* __restrict__ bl,
    float* __restrict__ dvals, float* __restrict__ base,
    unsigned short* __restrict__ Wf)
{
    int tid = threadIdx.x;
    if (blockIdx.x < 1024) {
        int idx = blockIdx.x * 256 + tid;       // 0..262143
        int k = idx >> 8, c = idx & 255;
        float w = Wl[idx];
        unsigned short h = f2bf(w);
        float r1 = w - bf2f(h);
        unsigned short m = f2bf(r1);
        float r2 = r1 - bf2f(m);
        unsigned short l = f2bf(r2);
        int kstep = k >> 5;
        int nt = c >> 4;
        int ln = (c & 15) + (((k & 31) >> 3) << 4);
        int e = k & 7;
        long o = (((long)(kstep * 3) * 16 + nt) * 64 + ln) * 8 + e;
        Wf[o]         = h;    // plane stride = 16*64*8 = 8192 u16
        Wf[o + 8192]  = m;
        Wf[o + 16384] = l;
        return;
    }
    // ---- dem MLP path (one block) ----
    __shared__ float h1s[NBATCH][H1DIM];
    __shared__ float dsh[NBATCH][DEMO];
    for (int idx = tid; idx < NBATCH * H1DIM; idx += 256) {
        int n = idx / H1DIM, o = idx % H1DIM;
        float s = b1[o];
        #pragma unroll
        for (int k = 0; k < DEMI; ++k) s += dem[n * DEMI + k] * W1[k * H1DIM + o];
        h1s[n][o] = fmaxf(s, 0.0f);
    }
    __syncthreads();
    for (int idx = tid; idx < NBATCH * DEMO; idx += 256) {
        int n = idx / DEMO, o = idx % DEMO;
        float s = b2[o];
        #pragma unroll
        for (int k = 0; k < H1DIM; ++k) s += h1s[n][k] * W2[k * DEMO + o];
        float dv = fmaxf(s, 0.0f);
        dsh[n][o] = dv;
        dvals[idx] = dv;
    }
    __syncthreads();
    for (int idx = tid; idx < NBATCH * CDIM; idx += 256) {
        int n = idx >> 8, c = idx & 255;
        float s = bl[c];
        #pragma unroll
        for (int k = 0; k < DEMO; ++k) s += dsh[n][k] * Wl[(KDIM + k) * CDIM + c];
        base[idx] = s;
    }
}

// ---------------------------------------------------------------------------
// K2: 3-way-bf16-split MFMA GEMM, software-pipelined (T3 minimum 2-phase).
// a*b ~= ah*bh + ah*bm + am*bh + ah*bl + al*bh + am*bm  (6 MFMA, err ~2^-24)
// Tile BM=128 x BN=128, BK=32, 4 waves (2x2), 64x64/wave, 16x16x32 bf16 MFMA.
// Pipeline: A-loads for k+1 issued AFTER the LDS-ready barrier -> HBM latency
// hides under the MFMA section. B-loads (L2-hit) at loop top hide under the
// A fp32->3xbf16 conversion VALU work.
// XCD-aware decode: the two cb-blocks sharing an A panel land on one XCD L2.
// ---------------------------------------------------------------------------
__global__ __launch_bounds__(256) void k_gemm(
    const float* __restrict__ ts0, const float* __restrict__ ts1,
    const float* __restrict__ ts2, const float* __restrict__ ts3,
    const unsigned short* __restrict__ Wf, const float* __restrict__ base,
    float* __restrict__ X)
{
    __shared__ unsigned short Af[3][8][64][8];   // [plane][mtile][lane][e] 24 KB
    __shared__ unsigned short Bf[3][8][64][8];   // [plane][ntile][lane][e] 24 KB

    const int tid  = threadIdx.x;
    const int lane = tid & 63;
    const int wid  = tid >> 6;

    // XCD-aware: xcd = bid&7 (round-robin dispatch); give each XCD a
    // contiguous logical range so cb-pairs (2m,2m+1) share an XCD L2.
    const int bid     = blockIdx.x;
    const int logical = (bid & 7) * 128 + (bid >> 3);   // bijective, 1024=8*128
    const int mb = logical >> 1;           // 0..511
    const int cb = (logical & 1) << 7;     // 0 / 128
    const int n  = mb >> 4;
    const int t0 = (mb & 15) << 7;

    const int kq  = tid & 1;
    const int am  = tid >> 1;              // 0..127
    const int amt = am >> 4, aml = am & 15;
    const long arow = ((long)(n * LSEQ + t0 + am)) * CDIM;

    f32x4 acc[4][4];
    #pragma unroll
    for (int i = 0; i < 4; ++i)
        #pragma unroll
        for (int j = 0; j < 4; ++j)
            #pragma unroll
            for (int r = 0; r < 4; ++r) acc[i][j][r] = 0.0f;

    const uint4* wsrc = (const uint4*)Wf;            // 16B units
    uint4* bdst = (uint4*)(&Bf[0][0][0][0]);

    // prologue: issue A loads for kstep 0
    float4 av[4];
    #pragma unroll
    for (int j = 0; j < 4; ++j)
        av[j] = *(const float4*)(ts0 + arow + kq * 4 + j * 8);

    for (int k0 = 0; k0 < KDIM; k0 += 32) {
        const int kstep = k0 >> 5;
        // B loads for THIS kstep (L2-resident; latency hidden under conversion)
        const long wbase = (long)kstep * 3072 + ((cb >> 4) << 6);   // uint4 units
        uint4 bv[6];
        #pragma unroll
        for (int p = 0; p < 3; ++p) {
            bv[p * 2 + 0] = wsrc[wbase + p * 1024 + tid];
            bv[p * 2 + 1] = wsrc[wbase + p * 1024 + tid + 256];
        }

        // convert A (av, loaded last iter) -> (h,m,l) bf16, write LDS planes
        #pragma unroll
        for (int j = 0; j < 4; ++j) {
            const float vv[4] = {av[j].x, av[j].y, av[j].z, av[j].w};
            us4 hv, mv, lv;
            #pragma unroll
            for (int q = 0; q < 4; ++q) {
                float v = vv[q];
                unsigned short h = f2bf(v);
                float r1 = v - bf2f(h);
                unsigned short m = f2bf(r1);
                float r2 = r1 - bf2f(m);
                unsigned short l = f2bf(r2);
                hv[q] = h; mv[q] = m; lv[q] = l;
            }
            const int ln = aml + (j << 4);     // k>>3 == j
            const int e0 = kq << 2;            // k&7 == 4*kq
            *(us4*)&Af[0][amt][ln][e0] = hv;
            *(us4*)&Af[1][amt][ln][e0] = mv;
            *(us4*)&Af[2][amt][ln][e0] = lv;
        }
        // B: linear copy (layout already fragment-order)
        #pragma unroll
        for (int p = 0; p < 3; ++p) {
            bdst[p * 512 + tid]       = bv[p * 2 + 0];
            bdst[p * 512 + 256 + tid] = bv[p * 2 + 1];
        }

        __syncthreads();   // LDS tile ready

        // issue A loads for kstep+1 NOW -> in flight during the MFMA section
        if (k0 + 32 < KDIM) {
            const int k1 = k0 + 32;
            const float* tspn = (k1 < 256) ? ts0 : (k1 < 512) ? ts1 : (k1 < 768) ? ts2 : ts3;
            const int joffn = k1 & 255;
            #pragma unroll
            for (int j = 0; j < 4; ++j)
                av[j] = *(const float4*)(tspn + arow + joffn + kq * 4 + j * 8);
        }

        // compute: wave quadrant (wmt, wnt), 16 tiles x 6 MFMAs
        const int wmt = (wid >> 1) << 2;
        const int wnt = (wid & 1) << 2;
        s16x8 ah[4], am2[4], al2[4];
        #pragma unroll
        for (int mt = 0; mt < 4; ++mt) {
            ah[mt]  = *(const s16x8*)&Af[0][wmt + mt][lane][0];
            am2[mt] = *(const s16x8*)&Af[1][wmt + mt][lane][0];
            al2[mt] = *(const s16x8*)&Af[2][wmt + mt][lane][0];
        }
        #pragma unroll
        for (int nt = 0; nt < 4; ++nt) {
            s16x8 bh = *(const s16x8*)&Bf[0][wnt + nt][lane][0];
            s16x8 bm = *(const s16x8*)&Bf[1][wnt + nt][lane][0];
            s16x8 bl = *(const s16x8*)&Bf[2][wnt + nt][lane][0];
            #pragma unroll
            for (int mt = 0; mt < 4; ++mt) {
                acc[mt][nt] = __builtin_amdgcn_mfma_f32_16x16x32_bf16(ah[mt],  bl, acc[mt][nt], 0, 0, 0);
                acc[mt][nt] = __builtin_amdgcn_mfma_f32_16x16x32_bf16(al2[mt], bh, acc[mt][nt], 0, 0, 0);
                acc[mt][nt] = __builtin_amdgcn_mfma_f32_16x16x32_bf16(am2[mt], bm, acc[mt][nt], 0, 0, 0);
                acc[mt][nt] = __builtin_amdgcn_mfma_f32_16x16x32_bf16(ah[mt],  bm, acc[mt][nt], 0, 0, 0);
                acc[mt][nt] = __builtin_amdgcn_mfma_f32_16x16x32_bf16(am2[mt], bh, acc[mt][nt], 0, 0, 0);
                acc[mt][nt] = __builtin_amdgcn_mfma_f32_16x16x32_bf16(ah[mt],  bh, acc[mt][nt], 0, 0, 0);
            }
        }

        __syncthreads();   // all waves done reading before next tile's writes
    }

    // epilogue: C/D layout col=lane&15, row=4*(lane>>4)+r. Lanes 0-15 write
    // 64B-contiguous channel runs -> clean full-line stores.
    const int rb = ((wid >> 1) << 6) + ((lane >> 4) << 2);
    const int cc = cb + ((wid & 1) << 6) + (lane & 15);
    float bb[4];
    #pragma unroll
    for (int nt = 0; nt < 4; ++nt) bb[nt] = base[n * CDIM + cc + nt * 16];

    #pragma unroll
    for (int mt = 0; mt < 4; ++mt) {
        #pragma unroll
        for (int r = 0; r < 4; ++r) {
            long off = ((long)(n * LSEQ) + t0 + rb + mt * 16 + r) * CDIM + cc;
            #pragma unroll
            for (int nt = 0; nt < 4; ++nt)
                X[off + nt * 16] = acc[mt][nt][r] + bb[nt];
        }
    }
}

// ---------------------------------------------------------------------------
// K3a: per-chunk aggregates (max + first-argmax + sum) over 64 t's
// ---------------------------------------------------------------------------
__global__ __launch_bounds__(256) void k_agg(
    const float* __restrict__ X,
    float* __restrict__ agm, float* __restrict__ ags, int* __restrict__ agi)
{
    int c = threadIdx.x;
    int n = blockIdx.x >> 5, ch = blockIdx.x & 31;
    int t0 = ch * CHLEN;
    const float* p = X + ((long)n * LSEQ + t0) * CDIM + c;
    float vm = -3.4e38f; int im = t0; float sm = 0.0f;
    #pragma unroll 4
    for (int tt = 0; tt < CHLEN; ++tt) {
        float v = p[(long)tt * CDIM];
        if (v > vm) { vm = v; im = t0 + tt; }
        sm += v;
    }
    int o = (n * NCHUNK + ch) * CDIM + c;
    agm[o] = vm; ags[o] = sm; agi[o] = im;
}

// ---------------------------------------------------------------------------
// K3b: exclusive prefix over chunks per (n,c)
// ---------------------------------------------------------------------------
__global__ __launch_bounds__(256) void k_pre(
    const float* __restrict__ agm, const float* __restrict__ ags, const int* __restrict__ agi,
    float* __restrict__ prm, float* __restrict__ prs, int* __restrict__ pri)
{
    int c = threadIdx.x;
    int n = blockIdx.x;
    float vm = -3.4e38f; int im = 0; float sm = 0.0f;
    for (int ch = 0; ch < NCHUNK; ++ch) {
        int o = (n * NCHUNK + ch) * CDIM + c;
        prm[o] = vm; pri[o] = im; prs[o] = sm;
        float av = agm[o]; float as = ags[o]; int ai = agi[o];
        if (av > vm) { vm = av; im = ai; }   // earlier chunk wins ties (av must be strictly >)
        sm += as;
    }
}

// ---------------------------------------------------------------------------
// K3c: final scan. Writes p_max_raw (in-place over X), cumsum S, and
//      time_inds (as float) into Ttmp ([n,t,c] order, staged in out0 section)
// ---------------------------------------------------------------------------
__global__ __launch_bounds__(256) void k_scan(
    float* __restrict__ X, float* __restrict__ S,
    const float* __restrict__ prm, const float* __restrict__ prs, const int* __restrict__ pri,
    float* __restrict__ Ttmp)
{
    int c = threadIdx.x;
    int n = blockIdx.x >> 5, ch = blockIdx.x & 31;
    int t0 = ch * CHLEN;
    int o = (n * NCHUNK + ch) * CDIM + c;
    float vm = prm[o]; int im = pri[o]; float sm = prs[o];
    long rb = ((long)n * LSEQ + t0) * CDIM + c;
    #pragma unroll 4
    for (int tt = 0; tt < CHLEN; ++tt) {
        int t = t0 + tt;
        long idx = rb + (long)tt * CDIM;
        float v = X[idx];
        if (v > vm) { vm = v; im = t; }
        sm += v;
        bool pad = t < (LSEQ - 1);
        float pm = pad ? fmaxf(vm, 0.0f) : vm;
        int ti = (pad && vm <= 0.0f) ? (t - (LSEQ - 1)) : im;
        X[idx] = pm;
        S[idx] = sm;
        Ttmp[idx] = (float)ti;
    }
}

// ---------------------------------------------------------------------------
// K5: merged dual transpose per (n, tile): [n,t,c] -> [n,c,t] for BOTH
//     Ttmp(->outTI) and X(->outACT). One block does both 64x64 tiles.
// ---------------------------------------------------------------------------
__global__ __launch_bounds__(256) void k_tr2(
    const float* __restrict__ srcT, float* __restrict__ dstT,
    const float* __restrict__ srcX, float* __restrict__ dstX)
{
    __shared__ float tileT[64][65];
    __shared__ float tileX[64][65];
    int n  = blockIdx.z;
    int tB = blockIdx.x;   // 0..31
    int cB = blockIdx.y;   // 0..3
    int tid = threadIdx.x;
    int i0 = tid >> 4;     // 0..15
    int j4 = tid & 15;     // 0..15

    long sbase = ((long)n * LSEQ + tB * 64) * CDIM + cB * 64;
    #pragma unroll
    for (int r = 0; r < 4; ++r) {
        int i = i0 + r * 16;
        float4 vT = *(const float4*)(srcT + sbase + (long)i * CDIM + j4 * 4);
        float4 vX = *(const float4*)(srcX + sbase + (long)i * CDIM + j4 * 4);
        tileT[i][j4 * 4 + 0] = vT.x; tileT[i][j4 * 4 + 1] = vT.y;
        tileT[i][j4 * 4 + 2] = vT.z; tileT[i][j4 * 4 + 3] = vT.w;
        tileX[i][j4 * 4 + 0] = vX.x; tileX[i][j4 * 4 + 1] = vX.y;
        tileX[i][j4 * 4 + 2] = vX.z; tileX[i][j4 * 4 + 3] = vX.w;
    }
    __syncthreads();
    long dbase = ((long)n * CDIM + cB * 64) * LSEQ + tB * 64;
    #pragma unroll
    for (int r = 0; r < 4; ++r) {
        int j = i0 + r * 16;   // c within tile
        float4 vT, vX;
        vT.x = tileT[j4 * 4 + 0][j]; vT.y = tileT[j4 * 4 + 1][j];
        vT.z = tileT[j4 * 4 + 2][j]; vT.w = tileT[j4 * 4 + 3][j];
        vX.x = tileX[j4 * 4 + 0][j]; vX.y = tileX[j4 * 4 + 1][j];
        vX.z = tileX[j4 * 4 + 2][j]; vX.w = tileX[j4 * 4 + 3][j];
        *(float4*)(dstT + dbase + (long)j * LSEQ + j4 * 4) = vT;
        *(float4*)(dstX + dbase + (long)j * LSEQ + j4 * 4) = vX;
    }
}

// ---------------------------------------------------------------------------
// K4: LayerNorm over c for p_max / p_avg / p_sum + dem tail -> out0 [n,t,788]
// ---------------------------------------------------------------------------
__global__ __launch_bounds__(256) void k_ln(
    const float* __restrict__ P, const float* __restrict__ S,
    const float* __restrict__ dvals, float* __restrict__ out0)
{
    int tid = threadIdx.x;
    int wid = tid >> 6, lane = tid & 63;
    long row = (long)blockIdx.x * 4 + wid;  // 0..65535
    int n = (int)(row >> 11);
    int t = (int)(row & 2047);
    long ib = row * CDIM + lane * 4;

    float4 p = *(const float4*)(P + ib);
    float4 s = *(const float4*)(S + ib);

    float sum_p = p.x + p.y + p.z + p.w;
    float sq_p  = p.x * p.x + p.y * p.y + p.z * p.z + p.w * p.w;
    float sum_s = s.x + s.y + s.z + s.w;
    float sq_s  = s.x * s.x + s.y * s.y + s.z * s.z + s.w * s.w;

    #pragma unroll
    for (int off = 32; off > 0; off >>= 1) {
        sum_p += __shfl_xor(sum_p, off);
        sq_p  += __shfl_xor(sq_p, off);
        sum_s += __shfl_xor(sum_s, off);
        sq_s  += __shfl_xor(sq_s, off);
    }

    const float inv = 1.0f / 256.0f;
    float mu_p = sum_p * inv;
    float var_p = sq_p * inv - mu_p * mu_p;
    float mu_s = sum_s * inv;
    float var_s = sq_s * inv - mu_s * mu_s;

    float r1 = 1.0f / sqrtf(var_p + LNEPS);
    const float a = 1.0f / 2048.0f;
    float r2 = a / sqrtf(a * a * var_s + LNEPS);
    float b = 1.0f / sqrtf((float)(t + 1));
    float r3 = b / sqrtf(b * b * var_s + LNEPS);

    float* ob = out0 + row * 788;
    float4 o1 = {(p.x - mu_p) * r1, (p.y - mu_p) * r1, (p.z - mu_p) * r1, (p.w - mu_p) * r1};
    *(float4*)(ob + lane * 4) = o1;
    float4 o2 = {(s.x - mu_s) * r2, (s.y - mu_s) * r2, (s.z - mu_s) * r2, (s.w - mu_s) * r2};
    *(float4*)(ob + 256 + lane * 4) = o2;
    float4 o3 = {(s.x - mu_s) * r3, (s.y - mu_s) * r3, (s.z - mu_s) * r3, (s.w - mu_s) * r3};
    *(float4*)(ob + 512 + lane * 4) = o3;
    if (lane < 5) {
        float4 dv = *(const float4*)(dvals + n * DEMO + lane * 4);
        *(float4*)(ob + 768 + lane * 4) = dv;
    }
}

// ---------------------------------------------------------------------------
extern "C" void kernel_launch(void* const* d_in, const int* in_sizes, int n_in,
                              void* d_out, int out_size, void* d_ws, size_t ws_size,
                              hipStream_t stream)
{
    const float* dem = (const float*)d_in[0];
    const float* ts0 = (const float*)d_in[1];
    const float* ts1 = (const float*)d_in[2];
    const float* ts2 = (const float*)d_in[3];
    const float* ts3 = (const float*)d_in[4];
    const float* W1  = (const float*)d_in[5];
    const float* b1  = (const float*)d_in[6];
    const float* W2  = (const float*)d_in[7];
    const float* b2  = (const float*)d_in[8];
    const float* Wl  = (const float*)d_in[9];
    const float* bl  = (const float*)d_in[10];

    float* ws = (float*)d_ws;
    float* X    = ws + OFF_X;
    float* S    = ws + OFF_S;
    float* agm  = ws + OFF_AGM;
    float* ags  = ws + OFF_AGS;
    int*   agi  = (int*)(ws + OFF_AGI);
    float* prm  = ws + OFF_PRM;
    float* prs  = ws + OFF_PRS;
    int*   pri  = (int*)(ws + OFF_PRI);
    float* dv   = ws + OFF_DV;
    float* base = ws + OFF_BASE;
    // Wf: 786432 u16 = 1.5 MB, aliases agm+ags (dead until k_agg)
    unsigned short* Wf = (unsigned short*)(ws + OFF_AGM);

    float* out    = (float*)d_out;
    float* outTI  = out + OUTTI_OFF;
    float* outACT = out + OUTACT_OFF;
    float* Ttmp   = out + OUT0_OFF;   // stage time_inds [n,t,c] here; k_ln overwrites last

    k_demwc<<<1025, 256, 0, stream>>>(dem, W1, b1, W2, b2, Wl, bl, dv, base, Wf);
    k_gemm<<<1024, 256, 0, stream>>>(ts0, ts1, ts2, ts3, Wf, base, X);
    k_agg<<<NBATCH * NCHUNK, 256, 0, stream>>>(X, agm, ags, agi);
    k_pre<<<NBATCH, 256, 0, stream>>>(agm, ags, agi, prm, prs, pri);
    k_scan<<<NBATCH * NCHUNK, 256, 0, stream>>>(X, S, prm, prs, pri, Ttmp);
    // dual transpose: Ttmp -> outTI  and  X(=p_max) -> outACT
    k_tr2<<<dim3(32, 4, 32), 256, 0, stream>>>(Ttmp, outTI, X, outACT);
    // LN + concat + dem tail -> out0 (overwrites Ttmp staging)
    k_ln<<<16384, 256, 0, stream>>>(X, S, dv, out);
}